// Round 17
// baseline (174.521 us; speedup 1.0000x reference)
//
#include <hip/hip_runtime.h>

#define NN 384
#define CC 128
#define NPOS (NN * NN)  // 147456
#define TPB 4           // pos-tiles per kP block (W amortization)

typedef short bf8_t __attribute__((ext_vector_type(8)));
typedef float f32x4_t __attribute__((ext_vector_type(4)));

#define MFMA16(a, b, c) __builtin_amdgcn_mfma_f32_16x16x32_bf16((a), (b), (c), 0, 0, 0)

__device__ __forceinline__ unsigned short f2bf(float f) {
  unsigned int u = __builtin_bit_cast(unsigned int, f);
  u += 0x7fffu + ((u >> 16) & 1u);  // RNE
  return (unsigned short)(u >> 16);
}
__device__ __forceinline__ float bf2f(unsigned short s) {
  return __builtin_bit_cast(float, ((unsigned int)s) << 16);
}
// fast sigmoid: v_exp2 + v_rcp; +-1ulp f32, invisible after bf16 rounding (R11).
__device__ __forceinline__ float sigm(float x) {
  float e = __builtin_amdgcn_exp2f(x * -1.44269504f);
  return __builtin_amdgcn_rcpf(1.0f + e);
}

// ---------------- kW: fp32 -> bf16 weight concat [768][128] -----------------
__global__ __launch_bounds__(256) void kW(const float* __restrict__ a,
                                          const float* __restrict__ b,
                                          const float* __restrict__ c,
                                          const float* __restrict__ d,
                                          const float* __restrict__ e,
                                          const float* __restrict__ f,
                                          unsigned short* __restrict__ o) {
  int idx = (blockIdx.x * 256 + threadIdx.x) * 4;
  const float* s = f;
  if (idx < 16384) s = a;
  else if (idx < 32768) s = b;
  else if (idx < 49152) s = c;
  else if (idx < 65536) s = d;
  else if (idx < 81920) s = e;
  int off = idx & 16383;
  float4 v = *(const float4*)(s + off);
  o[idx + 0] = f2bf(v.x);
  o[idx + 1] = f2bf(v.y);
  o[idx + 2] = f2bf(v.z);
  o[idx + 3] = f2bf(v.w);
}

// ---------------- kLN: LN1 streaming, x2d fp32 -> x_ln bf16 [pos][c] --------
__global__ __launch_bounds__(256) void kLN(const float* __restrict__ x,
                                           const float* __restrict__ n1g,
                                           const float* __restrict__ n1b,
                                           unsigned short* __restrict__ x_ln) {
  int t = threadIdx.x;
  int pos = blockIdx.x * 128 + (t >> 1);
  int half = t & 1;
  const float* xr = x + (size_t)pos * CC + half * 64;
  float v[64];
  float s = 0.f;
#pragma unroll
  for (int a = 0; a < 16; ++a) {
    float4 f4 = ((const float4*)xr)[a];
    v[4 * a + 0] = f4.x; v[4 * a + 1] = f4.y;
    v[4 * a + 2] = f4.z; v[4 * a + 3] = f4.w;
    s += f4.x + f4.y + f4.z + f4.w;
  }
  s += __shfl_xor(s, 1);
  float mu = s * (1.0f / CC);
  float vs = 0.f;
#pragma unroll
  for (int a = 0; a < 64; ++a) { float d = v[a] - mu; vs += d * d; }
  vs += __shfl_xor(vs, 1);
  float rs = rsqrtf(vs * (1.0f / CC) + 1e-5f);
  unsigned short* dst = x_ln + (size_t)pos * CC + half * 64;
#pragma unroll
  for (int a8 = 0; a8 < 8; ++a8) {
    union { bf8_t v8; unsigned short e[8]; } u;
#pragma unroll
    for (int e = 0; e < 8; ++e) {
      int c = half * 64 + a8 * 8 + e;
      u.e[e] = f2bf((v[a8 * 8 + e] - mu) * rs * n1g[c] + n1b[c]);
    }
    *(bf8_t*)(dst + a8 * 8) = u.v8;
  }
}

// ---------------- kP: projections + gates, TPB tiles per block --------------
// R17: in-loop barriers are LGKM-ONLY (s_waitcnt lgkmcnt(0) + s_barrier +
// sched_barrier(0)). __syncthreads drained vmcnt(0) at every tile, forcing
// each tile to wait for its 4 global_store_b128 to RETIRE at shared-HBM rates
// (~28us block wall time for ~3us compute). The barrier only needs LDS
// ordering (gather tile reuse); stores now drain under the next tile's COMP.
// The compiler's auto-counted vmcnt waits cover the xf register loads.
// (R15's race was a manual vmcnt(4) that counted ops not yet issued — the
// wait covered nothing. Rule: count outstanding AT THE WAIT POINT. Here there
// is no manual vmcnt at all.)
__global__ __launch_bounds__(256, 2) void kP(
    const unsigned short* __restrict__ x_ln, const unsigned short* __restrict__ wcat,
    const float* __restrict__ b1i, const float* __restrict__ b1is,
    const float* __restrict__ b1j, const float* __restrict__ b1js,
    const float* __restrict__ b3v, unsigned short* __restrict__ i_s,
    unsigned short* __restrict__ j_s, unsigned short* __restrict__ g3) {
  __shared__ __align__(16) unsigned short lds[24832];
  // shorts: [0,8192) Wv | [8192,16384) Wg | [16384,24576) gather | [24576,24832) bias
  unsigned short* gt = lds + 16384;
  float* bl = (float*)(lds + 24576);  // [0..63] V-bias, [64..127] G-bias

  int b = blockIdx.x;
  int xcd = b & 7, m = b >> 3;       // dispatch round-robins XCDs
  int group = m / 6, job = m % 6;    // 36 groups/XCD x 6 jobs
  int p = job >> 1, h = job & 1;
  int t = threadIdx.x, lane = t & 63, wave = t >> 6;
  int lr = lane & 15, lh = lane >> 4;

  // ---- W staging (once per block; pre-swizzled source, linear LDS dest) ----
  const unsigned short* Wv = wcat + (size_t)(p < 2 ? p * 2 : 4) * CC * CC + h * 64 * CC;
#pragma unroll
  for (int it = 0; it < 4; ++it) {
    int u = it * 256 + t;
    int row = u >> 4, sl = u & 15;
    int slg = sl ^ (row & 7);
    __builtin_amdgcn_global_load_lds(
        (const __attribute__((address_space(1))) unsigned int*)(Wv + row * CC + slg * 8),
        (__attribute__((address_space(3))) unsigned int*)(lds + u * 8), 16, 0, 0);
  }
  if (p < 2) {
    const unsigned short* Wg = Wv + CC * CC;
#pragma unroll
    for (int it = 0; it < 4; ++it) {
      int u = it * 256 + t;
      int row = u >> 4, sl = u & 15;
      int slg = sl ^ (row & 7);
      __builtin_amdgcn_global_load_lds(
          (const __attribute__((address_space(1))) unsigned int*)(Wg + row * CC + slg * 8),
          (__attribute__((address_space(3))) unsigned int*)(lds + 8192 + u * 8), 16, 0, 0);
    }
  }
  // ---- bias ----
  if (p < 2) {
    const float* bvp = p ? b1j : b1i;
    const float* bgp = p ? b1js : b1is;
    if (t < 16) ((float4*)bl)[t] = ((const float4*)(bvp + h * 64))[t];
    else if (t < 32) ((float4*)bl)[t] = ((const float4*)(bgp + h * 64))[t - 16];
  } else {
    if (t < 16) ((float4*)bl)[t] = ((const float4*)(b3v + h * 64))[t];
  }

  int pt0 = xcd * 144 + group * TPB;
  bf8_t xfA[2][4], xfB[2][4];
#define LOADXF(xf, tt)                                                               \
  {                                                                                  \
    int p0l = (pt0 + (tt)) * 128;                                                    \
    _Pragma("unroll") for (int nt = 0; nt < 2; ++nt)                                 \
        _Pragma("unroll") for (int kk = 0; kk < 4; ++kk)                             \
            xf[nt][kk] = *(const bf8_t*)(x_ln +                                      \
                                         (size_t)(p0l + wave * 32 + nt * 16 + lr) *  \
                                             CC + kk * 32 + lh * 8);                 \
  }
  LOADXF(xfA, 0);
  __syncthreads();  // full drain: W gload_lds + bias landed before any read

  f32x4_t z4 = {0.f, 0.f, 0.f, 0.f};
#pragma unroll
  for (int tt = 0; tt < TPB; ++tt) {
    int p0 = (pt0 + tt) * 128;
    bf8_t(&xfc)[2][4] = (tt & 1) ? xfB : xfA;
    bf8_t(&xfn)[2][4] = (tt & 1) ? xfA : xfB;
    if (tt + 1 < TPB) LOADXF(xfn, tt + 1);  // in flight during COMP

    f32x4_t accV[2][4], accG[2][4];
#pragma unroll
    for (int nt = 0; nt < 2; ++nt)
#pragma unroll
      for (int ct = 0; ct < 4; ++ct) { accV[nt][ct] = z4; accG[nt][ct] = z4; }
    if (p < 2) {
#pragma unroll
      for (int ct = 0; ct < 4; ++ct)
#pragma unroll
        for (int kk = 0; kk < 4; ++kk) {
          int rv = ct * 16 + lr;
          int slot = (kk * 4 + lh) ^ (rv & 7);
          bf8_t wv = *(const bf8_t*)&lds[rv * 128 + slot * 8];
          bf8_t wg = *(const bf8_t*)&lds[8192 + rv * 128 + slot * 8];
#pragma unroll
          for (int nt = 0; nt < 2; ++nt) {
            accV[nt][ct] = MFMA16(wv, xfc[nt][kk], accV[nt][ct]);  // D[c][pos]
            accG[nt][ct] = MFMA16(wg, xfc[nt][kk], accG[nt][ct]);
          }
        }
    } else {
#pragma unroll
      for (int ct = 0; ct < 4; ++ct)
#pragma unroll
        for (int kk = 0; kk < 4; ++kk) {
          int rv = ct * 16 + lr;
          int slot = (kk * 4 + lh) ^ (rv & 7);
          bf8_t wv = *(const bf8_t*)&lds[rv * 128 + slot * 8];
#pragma unroll
          for (int nt = 0; nt < 2; ++nt)
            accV[nt][ct] = MFMA16(xfc[nt][kk], wv, accV[nt][ct]);  // D[pos][c]
        }
    }

    if (p < 2) {
      // gated, gather [64c][128pos] swizzled (ds_write only)
#pragma unroll
      for (int nt = 0; nt < 2; ++nt)
#pragma unroll
        for (int ct = 0; ct < 4; ++ct)
#pragma unroll
          for (int r = 0; r < 4; ++r) {
            int cl = ct * 16 + lh * 4 + r;
            int pos = wave * 32 + nt * 16 + lr;
            float o = (accV[nt][ct][r] + bl[cl]) * sigm(accG[nt][ct][r] + bl[64 + cl]);
            int sw = ((ct * 4 + lh) & 7) << 4;
            gt[cl * 128 + (pos ^ sw)] = f2bf(o);
          }
      // LDS-only barrier: gather writes visible; global stores NOT drained
      asm volatile("s_waitcnt lgkmcnt(0)" ::: "memory");
      __builtin_amdgcn_s_barrier();
      __builtin_amdgcn_sched_barrier(0);
      unsigned short* dstm = p ? j_s : i_s;
#pragma unroll
      for (int it = 0; it < 4; ++it) {
        int u = it * 256 + t;
        int cl = u >> 4, ch = u & 15;
        int s = (cl >> 2) & 7;
        bf8_t v = *(const bf8_t*)&gt[cl * 128 + ((ch ^ (s << 1)) * 8)];
        *(bf8_t*)(dstm + (size_t)(h * 64 + cl) * NPOS + p0 + ch * 8) = v;
      }
    } else {
#pragma unroll
      for (int nt = 0; nt < 2; ++nt)
#pragma unroll
        for (int ct = 0; ct < 4; ++ct)
#pragma unroll
          for (int r = 0; r < 4; ++r) {
            int pos = wave * 32 + nt * 16 + lh * 4 + r;
            int cl = ct * 16 + lr;
            float o = sigm(accV[nt][ct][r] + bl[cl]);
            int slot = (cl >> 3) ^ (pos & 7);
            gt[pos * 64 + slot * 8 + (cl & 7)] = f2bf(o);
          }
      asm volatile("s_waitcnt lgkmcnt(0)" ::: "memory");
      __builtin_amdgcn_s_barrier();
      __builtin_amdgcn_sched_barrier(0);
#pragma unroll
      for (int it = 0; it < 4; ++it) {
        int u = it * 256 + t;
        int pos = u >> 3, ch = u & 7;
        int slot = ch ^ (pos & 7);
        bf8_t v = *(const bf8_t*)&gt[pos * 64 + slot * 8];
        *(bf8_t*)(g3 + (size_t)(p0 + pos) * CC + h * 64 + ch * 8) = v;
      }
    }
    // LDS-only barrier: this tile's gather ds_reads done -> next tile may
    // overwrite the gather tile. Global stores remain in flight (drain under
    // the next tile's COMP; kernel-end guarantees final completion).
    asm volatile("s_waitcnt lgkmcnt(0)" ::: "memory");
    __builtin_amdgcn_s_barrier();
    __builtin_amdgcn_sched_barrier(0);
  }
}

// ---------------- kB: per-channel GEMM -> out_pre BF16 [c][i][j] ------------
// R16: T3-minimum safe schedule — STAGE(next) at iteration top, ONE full
// __syncthreads per iteration (drain IS the guarantee). Gathered epilogue.
__global__ __launch_bounds__(256) void kB(const unsigned short* __restrict__ i_s,
                                          const unsigned short* __restrict__ j_s,
                                          unsigned short* __restrict__ out_pre) {
  __shared__ __align__(16) unsigned short lds[16384];  // shorts: A dbuf @0/4096, B dbuf @8192/12288
  int b = blockIdx.x;
  int logical = (b & 7) * 144 + (b >> 3);  // XCD-bijective swizzle (1152 = 8*144)
  int c = logical / 9;
  int tt = logical % 9;
  int i0 = (tt / 3) * 128, j0 = (tt % 3) * 128;
  const unsigned short* Ab = i_s + ((size_t)c * NN + i0) * NN;
  const unsigned short* Bb = j_s + ((size_t)c * NN + j0) * NN;
  int t = threadIdx.x, lane = t & 63, wave = t >> 6;
  int wi = (wave >> 1) * 64, wj = (wave & 1) * 64;
  int lr = lane & 15, lh = lane >> 4;
  int rsub = lane >> 2;        // row within 16-row chunk
  int ksub = (lane & 3) * 8;   // element offset within BK=32

  auto ISSUE = [&](int ks, int bsel) {
    int k0 = ks * 32;
#pragma unroll
    for (int half = 0; half < 2; ++half) {
      int r = half * 64 + wave * 16;  // wave-uniform base row
      __builtin_amdgcn_global_load_lds(
          (const __attribute__((address_space(1))) unsigned int*)(Ab + (size_t)(r + rsub) * NN + k0 + ksub),
          (__attribute__((address_space(3))) unsigned int*)(lds + bsel * 4096 + r * 32), 16, 0, 0);
      __builtin_amdgcn_global_load_lds(
          (const __attribute__((address_space(1))) unsigned int*)(Bb + (size_t)(r + rsub) * NN + k0 + ksub),
          (__attribute__((address_space(3))) unsigned int*)(lds + 8192 + bsel * 4096 + r * 32), 16, 0, 0);
    }
  };

  f32x4_t z4 = {0.f, 0.f, 0.f, 0.f};
  f32x4_t acc[4][4];
#pragma unroll
  for (int mt = 0; mt < 4; ++mt)
#pragma unroll
    for (int nt = 0; nt < 4; ++nt) acc[mt][nt] = z4;

  ISSUE(0, 0);
  __syncthreads();  // drain prologue stage
  for (int ks = 0; ks < 12; ++ks) {
    if (ks < 11) ISSUE(ks + 1, (ks + 1) & 1);
    const unsigned short* At = lds + (ks & 1) * 4096;
    const unsigned short* Bt = lds + 8192 + (ks & 1) * 4096;
    bf8_t af2[4], bf2[4];
#pragma unroll
    for (int mt = 0; mt < 4; ++mt) af2[mt] = *(const bf8_t*)&At[(wi + mt * 16 + lr) * 32 + lh * 8];
#pragma unroll
    for (int nt = 0; nt < 4; ++nt) bf2[nt] = *(const bf8_t*)&Bt[(wj + nt * 16 + lr) * 32 + lh * 8];
#pragma unroll
    for (int mt = 0; mt < 4; ++mt)
#pragma unroll
      for (int nt = 0; nt < 4; ++nt) acc[mt][nt] = MFMA16(af2[mt], bf2[nt], acc[mt][nt]);
    __syncthreads();  // full drain: next tile ready, this buffer free
  }

  // ---- epilogue: gather tile into dead LDS (granule-XOR), 256B-row stores --
#pragma unroll
  for (int mt = 0; mt < 4; ++mt)
#pragma unroll
    for (int nt = 0; nt < 4; ++nt)
#pragma unroll
      for (int r = 0; r < 4; ++r) {
        int i = wi + mt * 16 + lh * 4 + r;
        int j = wj + nt * 16 + lr;
        lds[i * 128 + (((j >> 3) ^ (i & 7)) * 8) + (j & 7)] = f2bf(acc[mt][nt][r]);
      }
  __syncthreads();
  unsigned short* obase = out_pre + ((size_t)c * NN + i0) * NN + j0;
#pragma unroll
  for (int it = 0; it < 8; ++it) {
    int g = it * 256 + t;
    int row = g >> 4, gsl = g & 15;
    bf8_t v = *(const bf8_t*)&lds[row * 128 + ((gsl ^ (row & 7)) * 8)];
    *(bf8_t*)(obase + (size_t)row * NN + gsl * 8) = v;
  }
}

// ---------------- kC: LDS-staged LN2 + w2 + gate -> out [p][c] fp32 ---------
__global__ __launch_bounds__(256, 2) void kC(const unsigned short* __restrict__ out_pre,
                                             const float* __restrict__ n2g,
                                             const float* __restrict__ n2b,
                                             const unsigned short* __restrict__ w2bf,
                                             const float* __restrict__ b2,
                                             const unsigned short* __restrict__ g3,
                                             float* __restrict__ out) {
  __shared__ __align__(16) unsigned short ldsu[17408];  // stage [128c][128pos] bf16 / overlay [128][136]
  int b = blockIdx.x;
  int ii = b / 3, j0 = (b % 3) * 128;
  int t = threadIdx.x, lane = t & 63, wave = t >> 6;

#pragma unroll
  for (int it = 0; it < 8; ++it) {
    int u = it * 256 + t;
    int c = u >> 4, jg = u & 15;
    __builtin_amdgcn_global_load_lds(
        (const __attribute__((address_space(1))) unsigned int*)(out_pre + ((size_t)c * NN + ii) * NN + j0 + jg * 8),
        (__attribute__((address_space(3))) unsigned int*)(ldsu + u * 8), 16, 0, 0);
  }
  __syncthreads();

  {  // LN2 from LDS: 2 threads/pos, 64 channels each
    int pos = t >> 1, half = t & 1;
    float v[64];
    float s = 0.f;
#pragma unroll
    for (int a = 0; a < 64; ++a) { v[a] = bf2f(ldsu[(half * 64 + a) * 128 + pos]); s += v[a]; }
    s += __shfl_xor(s, 1);
    float mu = s * (1.0f / CC);
    float vs = 0.f;
#pragma unroll
    for (int a = 0; a < 64; ++a) { float d = v[a] - mu; vs += d * d; }
    vs += __shfl_xor(vs, 1);
    float rs = rsqrtf(vs * (1.0f / CC) + 1e-5f);
    union { bf8_t v8[8]; unsigned short e[64]; } u;
#pragma unroll
    for (int a = 0; a < 64; ++a) {
      int c = half * 64 + a;
      u.e[a] = f2bf((v[a] - mu) * rs * n2g[c] + n2b[c]);
    }
    __syncthreads();
#pragma unroll
    for (int a8 = 0; a8 < 8; ++a8)
      *(bf8_t*)&ldsu[pos * 136 + half * 64 + a8 * 8] = u.v8[a8];
  }
  __syncthreads();

  int lr = lane & 15, lh = lane >> 4;
  bf8_t af2[2][4];
#pragma unroll
  for (int mt = 0; mt < 2; ++mt)
#pragma unroll
    for (int kk = 0; kk < 4; ++kk)
      af2[mt][kk] = *(const bf8_t*)&ldsu[(wave * 32 + mt * 16 + lr) * 136 + kk * 32 + lh * 8];
  f32x4_t z4 = {0.f, 0.f, 0.f, 0.f};
  f32x4_t acc[2][8];
#pragma unroll
  for (int mt = 0; mt < 2; ++mt)
#pragma unroll
    for (int nt = 0; nt < 8; ++nt) acc[mt][nt] = z4;
#pragma unroll
  for (int nt = 0; nt < 8; ++nt) {
#pragma unroll
    for (int kk = 0; kk < 4; ++kk) {
      bf8_t bw = *(const bf8_t*)(w2bf + (size_t)(nt * 16 + lr) * CC + kk * 32 + lh * 8);
#pragma unroll
      for (int mt = 0; mt < 2; ++mt) acc[mt][nt] = MFMA16(af2[mt][kk], bw, acc[mt][nt]);
    }
  }
#pragma unroll
  for (int mt = 0; mt < 2; ++mt)
#pragma unroll
    for (int nt = 0; nt < 8; ++nt)
#pragma unroll
      for (int r = 0; r < 4; ++r) {
        int posl = wave * 32 + mt * 16 + lh * 4 + r;
        int c = nt * 16 + lr;
        size_t p = (size_t)ii * NN + j0 + posl;
        float y = acc[mt][nt][r] + b2[c];
        out[p * CC + c] = y * bf2f(g3[p * CC + c]);
      }
}

extern "C" void kernel_launch(void* const* d_in, const int* in_sizes, int n_in,
                              void* d_out, int out_size, void* d_ws, size_t ws_size,
                              hipStream_t stream) {
  (void)in_sizes; (void)n_in; (void)out_size; (void)ws_size;
  const float* x2d  = (const float*)d_in[0];
  const float* n1g  = (const float*)d_in[1];
  const float* n1b  = (const float*)d_in[2];
  const float* n2g  = (const float*)d_in[3];
  const float* n2b  = (const float*)d_in[4];
  const float* w1i  = (const float*)d_in[5];
  const float* b1i  = (const float*)d_in[6];
  const float* w1j  = (const float*)d_in[7];
  const float* b1j  = (const float*)d_in[8];
  const float* w1is = (const float*)d_in[9];
  const float* b1is = (const float*)d_in[10];
  const float* w1js = (const float*)d_in[11];
  const float* b1js = (const float*)d_in[12];
  const float* w2   = (const float*)d_in[13];
  const float* b2   = (const float*)d_in[14];
  const float* w3   = (const float*)d_in[15];
  const float* b3   = (const float*)d_in[16];

  char* ws = (char*)d_ws;
  unsigned short* wcat = (unsigned short*)ws;            // 192 KiB (padded to 256 KiB)
  size_t TELEMS = (size_t)CC * NN * NN;                  // 18,874,368
  unsigned short* i_s  = (unsigned short*)(ws + 262144); // 36 MiB [c][p]
  unsigned short* j_s  = i_s + TELEMS;                   // 36 MiB [c][p]
  unsigned short* g3   = j_s + TELEMS;                   // 36 MiB [p][c]
  unsigned short* x_ln = g3 + TELEMS;                    // 36 MiB [p][c]
  // out_pre (36 MiB bf16) aliases x_ln: x_ln dead after kP, kB runs after kP.
  unsigned short* out_pre = x_ln;
  float* outp = (float*)d_out;

  kW<<<96, 256, 0, stream>>>(w1i, w1is, w1j, w1js, w3, w2, wcat);
  kLN<<<1152, 256, 0, stream>>>(x2d, n1g, n1b, x_ln);
  kP<<<1728, 256, 0, stream>>>(x_ln, wcat, b1i, b1is, b1j, b1js, b3, i_s, j_s, g3);
  kB<<<1152, 256, 0, stream>>>(i_s, j_s, out_pre);
  kC<<<1152, 256, 0, stream>>>(out_pre, n2g, n2b, wcat + 5 * CC * CC, b2, g3, outp);
}

// Round 18
// 173.146 us; speedup vs baseline: 1.0079x; 1.0079x over previous
//
#include <hip/hip_runtime.h>

#define NN 384
#define CC 128
#define NPOS (NN * NN)  // 147456
#define TPB 4           // pos-tiles per kP block (W amortization)

typedef short bf8_t __attribute__((ext_vector_type(8)));
typedef float f32x4_t __attribute__((ext_vector_type(4)));

#define MFMA16(a, b, c) __builtin_amdgcn_mfma_f32_16x16x32_bf16((a), (b), (c), 0, 0, 0)

__device__ __forceinline__ unsigned short f2bf(float f) {
  unsigned int u = __builtin_bit_cast(unsigned int, f);
  u += 0x7fffu + ((u >> 16) & 1u);  // RNE
  return (unsigned short)(u >> 16);
}
__device__ __forceinline__ float bf2f(unsigned short s) {
  return __builtin_bit_cast(float, ((unsigned int)s) << 16);
}
// fast sigmoid: v_exp2 + v_rcp; +-1ulp f32, invisible after bf16 rounding (R11).
__device__ __forceinline__ float sigm(float x) {
  float e = __builtin_amdgcn_exp2f(x * -1.44269504f);
  return __builtin_amdgcn_rcpf(1.0f + e);
}

// ---------------- kInit: kW (blocks 0-95) + kLN (blocks 96-1247) ------------
// kW: fp32 -> bf16 weight concat [768][128]; kLN: LN1 x2d fp32 -> x_ln bf16.
// Independent outputs; merged to save one launch + tail bubble.
__global__ __launch_bounds__(256) void kInit(
    const float* __restrict__ a, const float* __restrict__ b,
    const float* __restrict__ c, const float* __restrict__ d,
    const float* __restrict__ e, const float* __restrict__ f,
    unsigned short* __restrict__ o, const float* __restrict__ x,
    const float* __restrict__ n1g, const float* __restrict__ n1b,
    unsigned short* __restrict__ x_ln) {
  int blk = blockIdx.x;
  int t = threadIdx.x;
  if (blk < 96) {  // ---- kW ----
    int idx = (blk * 256 + t) * 4;
    const float* s = f;
    if (idx < 16384) s = a;
    else if (idx < 32768) s = b;
    else if (idx < 49152) s = c;
    else if (idx < 65536) s = d;
    else if (idx < 81920) s = e;
    int off = idx & 16383;
    float4 v = *(const float4*)(s + off);
    o[idx + 0] = f2bf(v.x);
    o[idx + 1] = f2bf(v.y);
    o[idx + 2] = f2bf(v.z);
    o[idx + 3] = f2bf(v.w);
    return;
  }
  // ---- kLN ----
  int pos = (blk - 96) * 128 + (t >> 1);
  int half = t & 1;
  const float* xr = x + (size_t)pos * CC + half * 64;
  float v[64];
  float s = 0.f;
#pragma unroll
  for (int a2 = 0; a2 < 16; ++a2) {
    float4 f4 = ((const float4*)xr)[a2];
    v[4 * a2 + 0] = f4.x; v[4 * a2 + 1] = f4.y;
    v[4 * a2 + 2] = f4.z; v[4 * a2 + 3] = f4.w;
    s += f4.x + f4.y + f4.z + f4.w;
  }
  s += __shfl_xor(s, 1);
  float mu = s * (1.0f / CC);
  float vs = 0.f;
#pragma unroll
  for (int a2 = 0; a2 < 64; ++a2) { float dd = v[a2] - mu; vs += dd * dd; }
  vs += __shfl_xor(vs, 1);
  float rs = rsqrtf(vs * (1.0f / CC) + 1e-5f);
  unsigned short* dst = x_ln + (size_t)pos * CC + half * 64;
#pragma unroll
  for (int a8 = 0; a8 < 8; ++a8) {
    union { bf8_t v8; unsigned short e2[8]; } u;
#pragma unroll
    for (int e2 = 0; e2 < 8; ++e2) {
      int cc2 = half * 64 + a8 * 8 + e2;
      u.e2[e2] = f2bf((v[a8 * 8 + e2] - mu) * rs * n1g[cc2] + n1b[cc2]);
    }
    *(bf8_t*)(dst + a8 * 8) = u.v8;
  }
}

// ---------------- kP: projections + gates, TPB tiles per block (R14/R16) ----
// kP declared done: ~64us invariant across 7 structural experiments (R6-R17).
__global__ __launch_bounds__(256, 2) void kP(
    const unsigned short* __restrict__ x_ln, const unsigned short* __restrict__ wcat,
    const float* __restrict__ b1i, const float* __restrict__ b1is,
    const float* __restrict__ b1j, const float* __restrict__ b1js,
    const float* __restrict__ b3v, unsigned short* __restrict__ i_s,
    unsigned short* __restrict__ j_s, unsigned short* __restrict__ g3) {
  __shared__ __align__(16) unsigned short lds[24832];
  // shorts: [0,8192) Wv | [8192,16384) Wg | [16384,24576) gather | [24576,24832) bias
  unsigned short* gt = lds + 16384;
  float* bl = (float*)(lds + 24576);  // [0..63] V-bias, [64..127] G-bias

  int b = blockIdx.x;
  int xcd = b & 7, m = b >> 3;       // dispatch round-robins XCDs
  int group = m / 6, job = m % 6;    // 36 groups/XCD x 6 jobs
  int p = job >> 1, h = job & 1;
  int t = threadIdx.x, lane = t & 63, wave = t >> 6;
  int lr = lane & 15, lh = lane >> 4;

  // ---- W staging (once per block; pre-swizzled source, linear LDS dest) ----
  const unsigned short* Wv = wcat + (size_t)(p < 2 ? p * 2 : 4) * CC * CC + h * 64 * CC;
#pragma unroll
  for (int it = 0; it < 4; ++it) {
    int u = it * 256 + t;
    int row = u >> 4, sl = u & 15;
    int slg = sl ^ (row & 7);
    __builtin_amdgcn_global_load_lds(
        (const __attribute__((address_space(1))) unsigned int*)(Wv + row * CC + slg * 8),
        (__attribute__((address_space(3))) unsigned int*)(lds + u * 8), 16, 0, 0);
  }
  if (p < 2) {
    const unsigned short* Wg = Wv + CC * CC;
#pragma unroll
    for (int it = 0; it < 4; ++it) {
      int u = it * 256 + t;
      int row = u >> 4, sl = u & 15;
      int slg = sl ^ (row & 7);
      __builtin_amdgcn_global_load_lds(
          (const __attribute__((address_space(1))) unsigned int*)(Wg + row * CC + slg * 8),
          (__attribute__((address_space(3))) unsigned int*)(lds + 8192 + u * 8), 16, 0, 0);
    }
  }
  // ---- bias ----
  if (p < 2) {
    const float* bvp = p ? b1j : b1i;
    const float* bgp = p ? b1js : b1is;
    if (t < 16) ((float4*)bl)[t] = ((const float4*)(bvp + h * 64))[t];
    else if (t < 32) ((float4*)bl)[t] = ((const float4*)(bgp + h * 64))[t - 16];
  } else {
    if (t < 16) ((float4*)bl)[t] = ((const float4*)(b3v + h * 64))[t];
  }

  int pt0 = xcd * 144 + group * TPB;
  bf8_t xfA[2][4], xfB[2][4];
#define LOADXF(xf, tt)                                                               \
  {                                                                                  \
    int p0l = (pt0 + (tt)) * 128;                                                    \
    _Pragma("unroll") for (int nt = 0; nt < 2; ++nt)                                 \
        _Pragma("unroll") for (int kk = 0; kk < 4; ++kk)                             \
            xf[nt][kk] = *(const bf8_t*)(x_ln +                                      \
                                         (size_t)(p0l + wave * 32 + nt * 16 + lr) *  \
                                             CC + kk * 32 + lh * 8);                 \
  }
  LOADXF(xfA, 0);
  __syncthreads();  // W + bias staged (vmcnt drained)

  f32x4_t z4 = {0.f, 0.f, 0.f, 0.f};
#pragma unroll
  for (int tt = 0; tt < TPB; ++tt) {
    int p0 = (pt0 + tt) * 128;
    bf8_t(&xfc)[2][4] = (tt & 1) ? xfB : xfA;
    bf8_t(&xfn)[2][4] = (tt & 1) ? xfA : xfB;
    if (tt + 1 < TPB) LOADXF(xfn, tt + 1);  // in flight during COMP

    f32x4_t accV[2][4], accG[2][4];
#pragma unroll
    for (int nt = 0; nt < 2; ++nt)
#pragma unroll
      for (int ct = 0; ct < 4; ++ct) { accV[nt][ct] = z4; accG[nt][ct] = z4; }
    if (p < 2) {
#pragma unroll
      for (int ct = 0; ct < 4; ++ct)
#pragma unroll
        for (int kk = 0; kk < 4; ++kk) {
          int rv = ct * 16 + lr;
          int slot = (kk * 4 + lh) ^ (rv & 7);
          bf8_t wv = *(const bf8_t*)&lds[rv * 128 + slot * 8];
          bf8_t wg = *(const bf8_t*)&lds[8192 + rv * 128 + slot * 8];
#pragma unroll
          for (int nt = 0; nt < 2; ++nt) {
            accV[nt][ct] = MFMA16(wv, xfc[nt][kk], accV[nt][ct]);  // D[c][pos]
            accG[nt][ct] = MFMA16(wg, xfc[nt][kk], accG[nt][ct]);
          }
        }
    } else {
#pragma unroll
      for (int ct = 0; ct < 4; ++ct)
#pragma unroll
        for (int kk = 0; kk < 4; ++kk) {
          int rv = ct * 16 + lr;
          int slot = (kk * 4 + lh) ^ (rv & 7);
          bf8_t wv = *(const bf8_t*)&lds[rv * 128 + slot * 8];
#pragma unroll
          for (int nt = 0; nt < 2; ++nt)
            accV[nt][ct] = MFMA16(xfc[nt][kk], wv, accV[nt][ct]);  // D[pos][c]
        }
    }

    if (p < 2) {
#pragma unroll
      for (int nt = 0; nt < 2; ++nt)
#pragma unroll
        for (int ct = 0; ct < 4; ++ct)
#pragma unroll
          for (int r = 0; r < 4; ++r) {
            int cl = ct * 16 + lh * 4 + r;
            int pos = wave * 32 + nt * 16 + lr;
            float o = (accV[nt][ct][r] + bl[cl]) * sigm(accG[nt][ct][r] + bl[64 + cl]);
            int sw = ((ct * 4 + lh) & 7) << 4;
            gt[cl * 128 + (pos ^ sw)] = f2bf(o);
          }
      __syncthreads();
      unsigned short* dstm = p ? j_s : i_s;
#pragma unroll
      for (int it = 0; it < 4; ++it) {
        int u = it * 256 + t;
        int cl = u >> 4, ch = u & 15;
        int s = (cl >> 2) & 7;
        bf8_t v = *(const bf8_t*)&gt[cl * 128 + ((ch ^ (s << 1)) * 8)];
        *(bf8_t*)(dstm + (size_t)(h * 64 + cl) * NPOS + p0 + ch * 8) = v;
      }
    } else {
#pragma unroll
      for (int nt = 0; nt < 2; ++nt)
#pragma unroll
        for (int ct = 0; ct < 4; ++ct)
#pragma unroll
          for (int r = 0; r < 4; ++r) {
            int pos = wave * 32 + nt * 16 + lh * 4 + r;
            int cl = ct * 16 + lr;
            float o = sigm(accV[nt][ct][r] + bl[cl]);
            int slot = (cl >> 3) ^ (pos & 7);
            gt[pos * 64 + slot * 8 + (cl & 7)] = f2bf(o);
          }
      __syncthreads();
#pragma unroll
      for (int it = 0; it < 4; ++it) {
        int u = it * 256 + t;
        int pos = u >> 3, ch = u & 7;
        int slot = ch ^ (pos & 7);
        bf8_t v = *(const bf8_t*)&gt[pos * 64 + slot * 8];
        *(bf8_t*)(g3 + (size_t)(p0 + pos) * CC + h * 64 + ch * 8) = v;
      }
    }
    __syncthreads();  // gather reads done before next tile's writes
  }
}

// ---------------- kB: per-channel GEMM -> out_pre BF16 [c][i][j] ------------
// R16: T3-minimum safe schedule — STAGE(next) at iteration top, ONE full
// __syncthreads per iteration (drain IS the guarantee). Gathered epilogue.
__global__ __launch_bounds__(256) void kB(const unsigned short* __restrict__ i_s,
                                          const unsigned short* __restrict__ j_s,
                                          unsigned short* __restrict__ out_pre) {
  __shared__ __align__(16) unsigned short lds[16384];  // shorts: A dbuf @0/4096, B dbuf @8192/12288
  int b = blockIdx.x;
  int logical = (b & 7) * 144 + (b >> 3);  // XCD-bijective swizzle (1152 = 8*144)
  int c = logical / 9;
  int tt = logical % 9;
  int i0 = (tt / 3) * 128, j0 = (tt % 3) * 128;
  const unsigned short* Ab = i_s + ((size_t)c * NN + i0) * NN;
  const unsigned short* Bb = j_s + ((size_t)c * NN + j0) * NN;
  int t = threadIdx.x, lane = t & 63, wave = t >> 6;
  int wi = (wave >> 1) * 64, wj = (wave & 1) * 64;
  int lr = lane & 15, lh = lane >> 4;
  int rsub = lane >> 2;        // row within 16-row chunk
  int ksub = (lane & 3) * 8;   // element offset within BK=32

  auto ISSUE = [&](int ks, int bsel) {
    int k0 = ks * 32;
#pragma unroll
    for (int half = 0; half < 2; ++half) {
      int r = half * 64 + wave * 16;  // wave-uniform base row
      __builtin_amdgcn_global_load_lds(
          (const __attribute__((address_space(1))) unsigned int*)(Ab + (size_t)(r + rsub) * NN + k0 + ksub),
          (__attribute__((address_space(3))) unsigned int*)(lds + bsel * 4096 + r * 32), 16, 0, 0);
      __builtin_amdgcn_global_load_lds(
          (const __attribute__((address_space(1))) unsigned int*)(Bb + (size_t)(r + rsub) * NN + k0 + ksub),
          (__attribute__((address_space(3))) unsigned int*)(lds + 8192 + bsel * 4096 + r * 32), 16, 0, 0);
    }
  };

  f32x4_t z4 = {0.f, 0.f, 0.f, 0.f};
  f32x4_t acc[4][4];
#pragma unroll
  for (int mt = 0; mt < 4; ++mt)
#pragma unroll
    for (int nt = 0; nt < 4; ++nt) acc[mt][nt] = z4;

  ISSUE(0, 0);
  __syncthreads();  // drain prologue stage
  for (int ks = 0; ks < 12; ++ks) {
    if (ks < 11) ISSUE(ks + 1, (ks + 1) & 1);
    const unsigned short* At = lds + (ks & 1) * 4096;
    const unsigned short* Bt = lds + 8192 + (ks & 1) * 4096;
    bf8_t af2[4], bf2[4];
#pragma unroll
    for (int mt = 0; mt < 4; ++mt) af2[mt] = *(const bf8_t*)&At[(wi + mt * 16 + lr) * 32 + lh * 8];
#pragma unroll
    for (int nt = 0; nt < 4; ++nt) bf2[nt] = *(const bf8_t*)&Bt[(wj + nt * 16 + lr) * 32 + lh * 8];
#pragma unroll
    for (int mt = 0; mt < 4; ++mt)
#pragma unroll
      for (int nt = 0; nt < 4; ++nt) acc[mt][nt] = MFMA16(af2[mt], bf2[nt], acc[mt][nt]);
    __syncthreads();  // full drain: next tile ready, this buffer free
  }

  // ---- epilogue: gather tile into dead LDS (granule-XOR), 256B-row stores --
#pragma unroll
  for (int mt = 0; mt < 4; ++mt)
#pragma unroll
    for (int nt = 0; nt < 4; ++nt)
#pragma unroll
      for (int r = 0; r < 4; ++r) {
        int i = wi + mt * 16 + lh * 4 + r;
        int j = wj + nt * 16 + lr;
        lds[i * 128 + (((j >> 3) ^ (i & 7)) * 8) + (j & 7)] = f2bf(acc[mt][nt][r]);
      }
  __syncthreads();
  unsigned short* obase = out_pre + ((size_t)c * NN + i0) * NN + j0;
#pragma unroll
  for (int it = 0; it < 8; ++it) {
    int g = it * 256 + t;
    int row = g >> 4, gsl = g & 15;
    bf8_t v = *(const bf8_t*)&lds[row * 128 + ((gsl ^ (row & 7)) * 8)];
    *(bf8_t*)(obase + (size_t)row * NN + gsl * 8) = v;
  }
}

// ---------------- kC: LDS-staged LN2 + w2 + gate -> out [p][c] fp32 ---------
// R18: the g3 gate tile (contiguous 32KB) is ALSO staged via global_load_lds
// (pre-swizzled source granules), replacing 64 scattered 2B global loads per
// thread in the epilogue — same fix class as R9's out_pre staging win.
__global__ __launch_bounds__(256, 2) void kC(const unsigned short* __restrict__ out_pre,
                                             const float* __restrict__ n2g,
                                             const float* __restrict__ n2b,
                                             const unsigned short* __restrict__ w2bf,
                                             const float* __restrict__ b2,
                                             const unsigned short* __restrict__ g3,
                                             float* __restrict__ out) {
  __shared__ __align__(16) unsigned short ldsu[17408];  // stage [128c][128pos] bf16 / overlay [128][136]
  __shared__ __align__(16) unsigned short g3t[16384];   // g3 tile [128pos][128c], src-swizzled
  int b = blockIdx.x;
  int ii = b / 3, j0 = (b % 3) * 128;
  int t = threadIdx.x, lane = t & 63, wave = t >> 6;

  // ---- stage out_pre tile [c][pos] (coalesced 256B rows) ----
#pragma unroll
  for (int it = 0; it < 8; ++it) {
    int u = it * 256 + t;
    int c = u >> 4, jg = u & 15;
    __builtin_amdgcn_global_load_lds(
        (const __attribute__((address_space(1))) unsigned int*)(out_pre + ((size_t)c * NN + ii) * NN + j0 + jg * 8),
        (__attribute__((address_space(3))) unsigned int*)(ldsu + u * 8), 16, 0, 0);
  }
  // ---- stage g3 tile [pos][c] (contiguous 32KB region), source pre-swizzle:
  // LDS[pos][slot] holds global granule slot^(pos&15); read side inverts.
#pragma unroll
  for (int it = 0; it < 8; ++it) {
    int u = it * 256 + t;
    int pos = u >> 4, gr = u & 15;
    int gs = gr ^ (pos & 15);
    __builtin_amdgcn_global_load_lds(
        (const __attribute__((address_space(1))) unsigned int*)(g3 + (size_t)(ii * NN + j0 + pos) * CC + gs * 8),
        (__attribute__((address_space(3))) unsigned int*)(g3t + u * 8), 16, 0, 0);
  }
  __syncthreads();

  {  // LN2 from LDS: 2 threads/pos, 64 channels each
    int pos = t >> 1, half = t & 1;
    float v[64];
    float s = 0.f;
#pragma unroll
    for (int a = 0; a < 64; ++a) { v[a] = bf2f(ldsu[(half * 64 + a) * 128 + pos]); s += v[a]; }
    s += __shfl_xor(s, 1);
    float mu = s * (1.0f / CC);
    float vs = 0.f;
#pragma unroll
    for (int a = 0; a < 64; ++a) { float d = v[a] - mu; vs += d * d; }
    vs += __shfl_xor(vs, 1);
    float rs = rsqrtf(vs * (1.0f / CC) + 1e-5f);
    union { bf8_t v8[8]; unsigned short e[64]; } u;
#pragma unroll
    for (int a = 0; a < 64; ++a) {
      int c = half * 64 + a;
      u.e[a] = f2bf((v[a] - mu) * rs * n2g[c] + n2b[c]);
    }
    __syncthreads();  // all staged reads done -> overlay MFMA tile
#pragma unroll
    for (int a8 = 0; a8 < 8; ++a8)
      *(bf8_t*)&ldsu[pos * 136 + half * 64 + a8 * 8] = u.v8[a8];
  }
  __syncthreads();

  int lr = lane & 15, lh = lane >> 4;
  bf8_t af2[2][4];
#pragma unroll
  for (int mt = 0; mt < 2; ++mt)
#pragma unroll
    for (int kk = 0; kk < 4; ++kk)
      af2[mt][kk] = *(const bf8_t*)&ldsu[(wave * 32 + mt * 16 + lr) * 136 + kk * 32 + lh * 8];
  f32x4_t z4 = {0.f, 0.f, 0.f, 0.f};
  f32x4_t acc[2][8];
#pragma unroll
  for (int mt = 0; mt < 2; ++mt)
#pragma unroll
    for (int nt = 0; nt < 8; ++nt) acc[mt][nt] = z4;
#pragma unroll
  for (int nt = 0; nt < 8; ++nt) {
#pragma unroll
    for (int kk = 0; kk < 4; ++kk) {
      bf8_t bw = *(const bf8_t*)(w2bf + (size_t)(nt * 16 + lr) * CC + kk * 32 + lh * 8);
#pragma unroll
      for (int mt = 0; mt < 2; ++mt) acc[mt][nt] = MFMA16(af2[mt][kk], bw, acc[mt][nt]);
    }
  }
#pragma unroll
  for (int mt = 0; mt < 2; ++mt)
#pragma unroll
    for (int nt = 0; nt < 8; ++nt)
#pragma unroll
      for (int r = 0; r < 4; ++r) {
        int posl = wave * 32 + mt * 16 + lh * 4 + r;
        int c = nt * 16 + lr;
        size_t p = (size_t)ii * NN + j0 + posl;
        float y = acc[mt][nt][r] + b2[c];
        // gate from staged LDS tile (read-side swizzle inverts source swizzle)
        float g = bf2f(g3t[posl * 128 + (((c >> 3) ^ (posl & 15)) * 8) + (c & 7)]);
        out[p * CC + c] = y * g;
      }
}

extern "C" void kernel_launch(void* const* d_in, const int* in_sizes, int n_in,
                              void* d_out, int out_size, void* d_ws, size_t ws_size,
                              hipStream_t stream) {
  (void)in_sizes; (void)n_in; (void)out_size; (void)ws_size;
  const float* x2d  = (const float*)d_in[0];
  const float* n1g  = (const float*)d_in[1];
  const float* n1b  = (const float*)d_in[2];
  const float* n2g  = (const float*)d_in[3];
  const float* n2b  = (const float*)d_in[4];
  const float* w1i  = (const float*)d_in[5];
  const float* b1i  = (const float*)d_in[6];
  const float* w1j  = (const float*)d_in[7];
  const float* b1j  = (const float*)d_in[8];
  const float* w1is = (const float*)d_in[9];
  const float* b1is = (const float*)d_in[10];
  const float* w1js = (const float*)d_in[11];
  const float* b1js = (const float*)d_in[12];
  const float* w2   = (const float*)d_in[13];
  const float* b2   = (const float*)d_in[14];
  const float* w3   = (const float*)d_in[15];
  const float* b3   = (const float*)d_in[16];

  char* ws = (char*)d_ws;
  unsigned short* wcat = (unsigned short*)ws;            // 192 KiB (padded to 256 KiB)
  size_t TELEMS = (size_t)CC * NN * NN;                  // 18,874,368
  unsigned short* i_s  = (unsigned short*)(ws + 262144); // 36 MiB [c][p]
  unsigned short* j_s  = i_s + TELEMS;                   // 36 MiB [c][p]
  unsigned short* g3   = j_s + TELEMS;                   // 36 MiB [p][c]
  unsigned short* x_ln = g3 + TELEMS;                    // 36 MiB [p][c]
  // out_pre (36 MiB bf16) aliases x_ln: x_ln dead after kP, kB runs after kP.
  unsigned short* out_pre = x_ln;
  float* outp = (float*)d_out;

  kInit<<<1248, 256, 0, stream>>>(w1i, w1is, w1j, w1js, w3, w2, wcat, x2d, n1g, n1b, x_ln);
  kP<<<1728, 256, 0, stream>>>(x_ln, wcat, b1i, b1is, b1j, b1js, b3, i_s, j_s, g3);
  kB<<<1152, 256, 0, stream>>>(i_s, j_s, out_pre);
  kC<<<1152, 256, 0, stream>>>(out_pre, n2g, n2b, wcat + 5 * CC * CC, b2, g3, outp);
}

// Round 19
// 164.748 us; speedup vs baseline: 1.0593x; 1.0510x over previous
//
#include <hip/hip_runtime.h>
#include <hip/hip_bf16.h>

#define NN 384
#define CC 128
#define NPOS (NN * NN)  // 147456
#define TPB 4           // pos-tiles per kP block (W amortization)

typedef short bf8_t __attribute__((ext_vector_type(8)));
typedef float f32x4_t __attribute__((ext_vector_type(4)));

#define MFMA16(a, b, c) __builtin_amdgcn_mfma_f32_16x16x32_bf16((a), (b), (c), 0, 0, 0)

// native cast -> compiler emits packed v_cvt_pk_bf16_f32 for adjacent pairs
// (m240: scalar casts get packed by the compiler; hand-written asm does NOT).
__device__ __forceinline__ unsigned short f2bf(float f) {
  return __builtin_bit_cast(unsigned short, __float2bfloat16(f));
}
__device__ __forceinline__ float bf2f(unsigned short s) {
  return __builtin_bit_cast(float, ((unsigned int)s) << 16);
}
// fast sigmoid: v_exp2 + v_rcp; +-1ulp f32, invisible after bf16 rounding (R11).
__device__ __forceinline__ float sigm(float x) {
  float e = __builtin_amdgcn_exp2f(x * -1.44269504f);
  return __builtin_amdgcn_rcpf(1.0f + e);
}

// ---------------- kInit: kW (blocks 0-95) + kLN (blocks 96-1247) ------------
__global__ __launch_bounds__(256) void kInit(
    const float* __restrict__ a, const float* __restrict__ b,
    const float* __restrict__ c, const float* __restrict__ d,
    const float* __restrict__ e, const float* __restrict__ f,
    unsigned short* __restrict__ o, const float* __restrict__ x,
    const float* __restrict__ n1g, const float* __restrict__ n1b,
    unsigned short* __restrict__ x_ln) {
  int blk = blockIdx.x;
  int t = threadIdx.x;
  if (blk < 96) {  // ---- kW ----
    int idx = (blk * 256 + t) * 4;
    const float* s = f;
    if (idx < 16384) s = a;
    else if (idx < 32768) s = b;
    else if (idx < 49152) s = c;
    else if (idx < 65536) s = d;
    else if (idx < 81920) s = e;
    int off = idx & 16383;
    float4 v = *(const float4*)(s + off);
    o[idx + 0] = f2bf(v.x);
    o[idx + 1] = f2bf(v.y);
    o[idx + 2] = f2bf(v.z);
    o[idx + 3] = f2bf(v.w);
    return;
  }
  // ---- kLN ----
  int pos = (blk - 96) * 128 + (t >> 1);
  int half = t & 1;
  const float* xr = x + (size_t)pos * CC + half * 64;
  float v[64];
  float s = 0.f;
#pragma unroll
  for (int a2 = 0; a2 < 16; ++a2) {
    float4 f4 = ((const float4*)xr)[a2];
    v[4 * a2 + 0] = f4.x; v[4 * a2 + 1] = f4.y;
    v[4 * a2 + 2] = f4.z; v[4 * a2 + 3] = f4.w;
    s += f4.x + f4.y + f4.z + f4.w;
  }
  s += __shfl_xor(s, 1);
  float mu = s * (1.0f / CC);
  float vs = 0.f;
#pragma unroll
  for (int a2 = 0; a2 < 64; ++a2) { float dd = v[a2] - mu; vs += dd * dd; }
  vs += __shfl_xor(vs, 1);
  float rs = rsqrtf(vs * (1.0f / CC) + 1e-5f);
  unsigned short* dst = x_ln + (size_t)pos * CC + half * 64;
#pragma unroll
  for (int a8 = 0; a8 < 8; ++a8) {
    union { bf8_t v8; unsigned short e2[8]; } u;
#pragma unroll
    for (int e2 = 0; e2 < 8; ++e2) {
      int cc2 = half * 64 + a8 * 8 + e2;
      u.e2[e2] = f2bf((v[a8 * 8 + e2] - mu) * rs * n1g[cc2] + n1b[cc2]);
    }
    *(bf8_t*)(dst + a8 * 8) = u.v8;
  }
}

// ---------------- kP: projections + gates, TPB tiles per block --------------
// R19: bias folded into MFMA C-in (acc init = bias regs, HW adds C) — removes
// 64 f32 adds/thread/tile; native bf16 casts get pk-packed by the compiler.
__global__ __launch_bounds__(256, 2) void kP(
    const unsigned short* __restrict__ x_ln, const unsigned short* __restrict__ wcat,
    const float* __restrict__ b1i, const float* __restrict__ b1is,
    const float* __restrict__ b1j, const float* __restrict__ b1js,
    const float* __restrict__ b3v, unsigned short* __restrict__ i_s,
    unsigned short* __restrict__ j_s, unsigned short* __restrict__ g3) {
  __shared__ __align__(16) unsigned short lds[24832];
  // shorts: [0,8192) Wv | [8192,16384) Wg | [16384,24576) gather | [24576,24832) bias
  unsigned short* gt = lds + 16384;
  float* bl = (float*)(lds + 24576);  // [0..63] V-bias, [64..127] G-bias

  int b = blockIdx.x;
  int xcd = b & 7, m = b >> 3;       // dispatch round-robins XCDs
  int group = m / 6, job = m % 6;    // 36 groups/XCD x 6 jobs
  int p = job >> 1, h = job & 1;
  int t = threadIdx.x, lane = t & 63, wave = t >> 6;
  int lr = lane & 15, lh = lane >> 4;

  // ---- W staging (once per block; pre-swizzled source, linear LDS dest) ----
  const unsigned short* Wv = wcat + (size_t)(p < 2 ? p * 2 : 4) * CC * CC + h * 64 * CC;
#pragma unroll
  for (int it = 0; it < 4; ++it) {
    int u = it * 256 + t;
    int row = u >> 4, sl = u & 15;
    int slg = sl ^ (row & 7);
    __builtin_amdgcn_global_load_lds(
        (const __attribute__((address_space(1))) unsigned int*)(Wv + row * CC + slg * 8),
        (__attribute__((address_space(3))) unsigned int*)(lds + u * 8), 16, 0, 0);
  }
  if (p < 2) {
    const unsigned short* Wg = Wv + CC * CC;
#pragma unroll
    for (int it = 0; it < 4; ++it) {
      int u = it * 256 + t;
      int row = u >> 4, sl = u & 15;
      int slg = sl ^ (row & 7);
      __builtin_amdgcn_global_load_lds(
          (const __attribute__((address_space(1))) unsigned int*)(Wg + row * CC + slg * 8),
          (__attribute__((address_space(3))) unsigned int*)(lds + 8192 + u * 8), 16, 0, 0);
    }
  }
  // ---- bias to LDS ----
  if (p < 2) {
    const float* bvp = p ? b1j : b1i;
    const float* bgp = p ? b1js : b1is;
    if (t < 16) ((float4*)bl)[t] = ((const float4*)(bvp + h * 64))[t];
    else if (t < 32) ((float4*)bl)[t] = ((const float4*)(bgp + h * 64))[t - 16];
  } else {
    if (t < 16) ((float4*)bl)[t] = ((const float4*)(b3v + h * 64))[t];
  }

  int pt0 = xcd * 144 + group * TPB;
  bf8_t xfA[2][4], xfB[2][4];
#define LOADXF(xf, tt)                                                               \
  {                                                                                  \
    int p0l = (pt0 + (tt)) * 128;                                                    \
    _Pragma("unroll") for (int nt = 0; nt < 2; ++nt)                                 \
        _Pragma("unroll") for (int kk = 0; kk < 4; ++kk)                             \
            xf[nt][kk] = *(const bf8_t*)(x_ln +                                      \
                                         (size_t)(p0l + wave * 32 + nt * 16 + lr) *  \
                                             CC + kk * 32 + lh * 8);                 \
  }
  LOADXF(xfA, 0);
  __syncthreads();  // W + bias staged (vmcnt drained)

  // ---- bias prefetch to registers (feeds acc C-in init) ----
  float blv[16], blg[16];
  if (p < 2) {
#pragma unroll
    for (int ct = 0; ct < 4; ++ct)
#pragma unroll
      for (int r = 0; r < 4; ++r) {
        blv[ct * 4 + r] = bl[ct * 16 + lh * 4 + r];   // row = channel
        blg[ct * 4 + r] = bl[64 + ct * 16 + lh * 4 + r];
      }
  } else {
#pragma unroll
    for (int ct = 0; ct < 4; ++ct) blv[ct] = bl[ct * 16 + lr];  // col = channel
  }

#pragma unroll
  for (int tt = 0; tt < TPB; ++tt) {
    int p0 = (pt0 + tt) * 128;
    bf8_t(&xfc)[2][4] = (tt & 1) ? xfB : xfA;
    bf8_t(&xfn)[2][4] = (tt & 1) ? xfA : xfB;
    if (tt + 1 < TPB) LOADXF(xfn, tt + 1);  // in flight during COMP

    f32x4_t accV[2][4], accG[2][4];
    // C-in = bias (MFMA adds C in HW; epilogue add eliminated)
#pragma unroll
    for (int nt = 0; nt < 2; ++nt)
#pragma unroll
      for (int ct = 0; ct < 4; ++ct)
#pragma unroll
        for (int r = 0; r < 4; ++r) {
          if (p < 2) {
            accV[nt][ct][r] = blv[ct * 4 + r];
            accG[nt][ct][r] = blg[ct * 4 + r];
          } else {
            accV[nt][ct][r] = blv[ct];
            accG[nt][ct][r] = 0.f;
          }
        }
    if (p < 2) {
#pragma unroll
      for (int ct = 0; ct < 4; ++ct)
#pragma unroll
        for (int kk = 0; kk < 4; ++kk) {
          int rv = ct * 16 + lr;
          int slot = (kk * 4 + lh) ^ (rv & 7);
          bf8_t wv = *(const bf8_t*)&lds[rv * 128 + slot * 8];
          bf8_t wg = *(const bf8_t*)&lds[8192 + rv * 128 + slot * 8];
#pragma unroll
          for (int nt = 0; nt < 2; ++nt) {
            accV[nt][ct] = MFMA16(wv, xfc[nt][kk], accV[nt][ct]);  // D[c][pos]
            accG[nt][ct] = MFMA16(wg, xfc[nt][kk], accG[nt][ct]);
          }
        }
    } else {
#pragma unroll
      for (int ct = 0; ct < 4; ++ct)
#pragma unroll
        for (int kk = 0; kk < 4; ++kk) {
          int rv = ct * 16 + lr;
          int slot = (kk * 4 + lh) ^ (rv & 7);
          bf8_t wv = *(const bf8_t*)&lds[rv * 128 + slot * 8];
#pragma unroll
          for (int nt = 0; nt < 2; ++nt)
            accV[nt][ct] = MFMA16(xfc[nt][kk], wv, accV[nt][ct]);  // D[pos][c]
        }
    }

    if (p < 2) {
#pragma unroll
      for (int nt = 0; nt < 2; ++nt)
#pragma unroll
        for (int ct = 0; ct < 4; ++ct)
#pragma unroll
          for (int r = 0; r < 4; ++r) {
            int cl = ct * 16 + lh * 4 + r;
            int pos = wave * 32 + nt * 16 + lr;
            float o = accV[nt][ct][r] * sigm(accG[nt][ct][r]);
            int sw = ((ct * 4 + lh) & 7) << 4;
            gt[cl * 128 + (pos ^ sw)] = f2bf(o);
          }
      __syncthreads();
      unsigned short* dstm = p ? j_s : i_s;
#pragma unroll
      for (int it = 0; it < 4; ++it) {
        int u = it * 256 + t;
        int cl = u >> 4, ch = u & 15;
        int s = (cl >> 2) & 7;
        bf8_t v = *(const bf8_t*)&gt[cl * 128 + ((ch ^ (s << 1)) * 8)];
        *(bf8_t*)(dstm + (size_t)(h * 64 + cl) * NPOS + p0 + ch * 8) = v;
      }
    } else {
#pragma unroll
      for (int nt = 0; nt < 2; ++nt)
#pragma unroll
        for (int ct = 0; ct < 4; ++ct)
#pragma unroll
          for (int r = 0; r < 4; ++r) {
            int pos = wave * 32 + nt * 16 + lh * 4 + r;
            int cl = ct * 16 + lr;
            float o = sigm(accV[nt][ct][r]);
            int slot = (cl >> 3) ^ (pos & 7);
            gt[pos * 64 + slot * 8 + (cl & 7)] = f2bf(o);
          }
      __syncthreads();
#pragma unroll
      for (int it = 0; it < 4; ++it) {
        int u = it * 256 + t;
        int pos = u >> 3, ch = u & 7;
        int slot = ch ^ (pos & 7);
        bf8_t v = *(const bf8_t*)&gt[pos * 64 + slot * 8];
        *(bf8_t*)(g3 + (size_t)(p0 + pos) * CC + h * 64 + ch * 8) = v;
      }
    }
    __syncthreads();  // gather reads done before next tile's writes
  }
}

// ---------------- kB: per-channel GEMM -> out_pre BF16 [c][i][j] ------------
__global__ __launch_bounds__(256) void kB(const unsigned short* __restrict__ i_s,
                                          const unsigned short* __restrict__ j_s,
                                          unsigned short* __restrict__ out_pre) {
  __shared__ __align__(16) unsigned short lds[16384];  // shorts: A dbuf @0/4096, B dbuf @8192/12288
  int b = blockIdx.x;
  int logical = (b & 7) * 144 + (b >> 3);  // XCD-bijective swizzle (1152 = 8*144)
  int c = logical / 9;
  int tt = logical % 9;
  int i0 = (tt / 3) * 128, j0 = (tt % 3) * 128;
  const unsigned short* Ab = i_s + ((size_t)c * NN + i0) * NN;
  const unsigned short* Bb = j_s + ((size_t)c * NN + j0) * NN;
  int t = threadIdx.x, lane = t & 63, wave = t >> 6;
  int wi = (wave >> 1) * 64, wj = (wave & 1) * 64;
  int lr = lane & 15, lh = lane >> 4;
  int rsub = lane >> 2;
  int ksub = (lane & 3) * 8;

  auto ISSUE = [&](int ks, int bsel) {
    int k0 = ks * 32;
#pragma unroll
    for (int half = 0; half < 2; ++half) {
      int r = half * 64 + wave * 16;
      __builtin_amdgcn_global_load_lds(
          (const __attribute__((address_space(1))) unsigned int*)(Ab + (size_t)(r + rsub) * NN + k0 + ksub),
          (__attribute__((address_space(3))) unsigned int*)(lds + bsel * 4096 + r * 32), 16, 0, 0);
      __builtin_amdgcn_global_load_lds(
          (const __attribute__((address_space(1))) unsigned int*)(Bb + (size_t)(r + rsub) * NN + k0 + ksub),
          (__attribute__((address_space(3))) unsigned int*)(lds + 8192 + bsel * 4096 + r * 32), 16, 0, 0);
    }
  };

  f32x4_t z4 = {0.f, 0.f, 0.f, 0.f};
  f32x4_t acc[4][4];
#pragma unroll
  for (int mt = 0; mt < 4; ++mt)
#pragma unroll
    for (int nt = 0; nt < 4; ++nt) acc[mt][nt] = z4;

  ISSUE(0, 0);
  __syncthreads();
  for (int ks = 0; ks < 12; ++ks) {
    if (ks < 11) ISSUE(ks + 1, (ks + 1) & 1);
    const unsigned short* At = lds + (ks & 1) * 4096;
    const unsigned short* Bt = lds + 8192 + (ks & 1) * 4096;
    bf8_t af2[4], bf2[4];
#pragma unroll
    for (int mt = 0; mt < 4; ++mt) af2[mt] = *(const bf8_t*)&At[(wi + mt * 16 + lr) * 32 + lh * 8];
#pragma unroll
    for (int nt = 0; nt < 4; ++nt) bf2[nt] = *(const bf8_t*)&Bt[(wj + nt * 16 + lr) * 32 + lh * 8];
#pragma unroll
    for (int mt = 0; mt < 4; ++mt)
#pragma unroll
      for (int nt = 0; nt < 4; ++nt) acc[mt][nt] = MFMA16(af2[mt], bf2[nt], acc[mt][nt]);
    __syncthreads();
  }

  // ---- epilogue: gather tile into dead LDS (granule-XOR), 256B-row stores --
#pragma unroll
  for (int mt = 0; mt < 4; ++mt)
#pragma unroll
    for (int nt = 0; nt < 4; ++nt)
#pragma unroll
      for (int r = 0; r < 4; ++r) {
        int i = wi + mt * 16 + lh * 4 + r;
        int j = wj + nt * 16 + lr;
        lds[i * 128 + (((j >> 3) ^ (i & 7)) * 8) + (j & 7)] = f2bf(acc[mt][nt][r]);
      }
  __syncthreads();
  unsigned short* obase = out_pre + ((size_t)c * NN + i0) * NN + j0;
#pragma unroll
  for (int it = 0; it < 8; ++it) {
    int g = it * 256 + t;
    int row = g >> 4, gsl = g & 15;
    bf8_t v = *(const bf8_t*)&lds[row * 128 + ((gsl ^ (row & 7)) * 8)];
    *(bf8_t*)(obase + (size_t)row * NN + gsl * 8) = v;
  }
}

// ---------------- kC: LDS-staged LN2 + w2 + gate -> out [p][c] fp32 ---------
// R19: b2 bias folded into MFMA C-in; g3 staged (R18); native pk-packed casts.
__global__ __launch_bounds__(256, 2) void kC(const unsigned short* __restrict__ out_pre,
                                             const float* __restrict__ n2g,
                                             const float* __restrict__ n2b,
                                             const unsigned short* __restrict__ w2bf,
                                             const float* __restrict__ b2,
                                             const unsigned short* __restrict__ g3,
                                             float* __restrict__ out) {
  __shared__ __align__(16) unsigned short ldsu[17408];  // stage [128c][128pos] bf16 / overlay [128][136]
  __shared__ __align__(16) unsigned short g3t[16384];   // g3 tile [128pos][128c], src-swizzled
  int b = blockIdx.x;
  int ii = b / 3, j0 = (b % 3) * 128;
  int t = threadIdx.x, lane = t & 63, wave = t >> 6;

#pragma unroll
  for (int it = 0; it < 8; ++it) {
    int u = it * 256 + t;
    int c = u >> 4, jg = u & 15;
    __builtin_amdgcn_global_load_lds(
        (const __attribute__((address_space(1))) unsigned int*)(out_pre + ((size_t)c * NN + ii) * NN + j0 + jg * 8),
        (__attribute__((address_space(3))) unsigned int*)(ldsu + u * 8), 16, 0, 0);
  }
#pragma unroll
  for (int it = 0; it < 8; ++it) {
    int u = it * 256 + t;
    int pos = u >> 4, gr = u & 15;
    int gs = gr ^ (pos & 15);
    __builtin_amdgcn_global_load_lds(
        (const __attribute__((address_space(1))) unsigned int*)(g3 + (size_t)(ii * NN + j0 + pos) * CC + gs * 8),
        (__attribute__((address_space(3))) unsigned int*)(g3t + u * 8), 16, 0, 0);
  }
  __syncthreads();

  {  // LN2 from LDS: 2 threads/pos, 64 channels each
    int pos = t >> 1, half = t & 1;
    float v[64];
    float s = 0.f;
#pragma unroll
    for (int a = 0; a < 64; ++a) { v[a] = bf2f(ldsu[(half * 64 + a) * 128 + pos]); s += v[a]; }
    s += __shfl_xor(s, 1);
    float mu = s * (1.0f / CC);
    float vs = 0.f;
#pragma unroll
    for (int a = 0; a < 64; ++a) { float d = v[a] - mu; vs += d * d; }
    vs += __shfl_xor(vs, 1);
    float rs = rsqrtf(vs * (1.0f / CC) + 1e-5f);
    union { bf8_t v8[8]; unsigned short e[64]; } u;
#pragma unroll
    for (int a = 0; a < 64; ++a) {
      int c = half * 64 + a;
      u.e[a] = f2bf((v[a] - mu) * rs * n2g[c] + n2b[c]);
    }
    __syncthreads();  // all staged reads done -> overlay MFMA tile
#pragma unroll
    for (int a8 = 0; a8 < 8; ++a8)
      *(bf8_t*)&ldsu[pos * 136 + half * 64 + a8 * 8] = u.v8[a8];
  }
  __syncthreads();

  int lr = lane & 15, lh = lane >> 4;
  // b2 bias -> regs (col c = nt*16+lr; same for all 4 acc elements)
  float b2r[8];
#pragma unroll
  for (int nt = 0; nt < 8; ++nt) b2r[nt] = b2[nt * 16 + lr];
  bf8_t af2[2][4];
#pragma unroll
  for (int mt = 0; mt < 2; ++mt)
#pragma unroll
    for (int kk = 0; kk < 4; ++kk)
      af2[mt][kk] = *(const bf8_t*)&ldsu[(wave * 32 + mt * 16 + lr) * 136 + kk * 32 + lh * 8];
  f32x4_t acc[2][8];
#pragma unroll
  for (int mt = 0; mt < 2; ++mt)
#pragma unroll
    for (int nt = 0; nt < 8; ++nt)
#pragma unroll
      for (int r = 0; r < 4; ++r) acc[mt][nt][r] = b2r[nt];  // C-in = bias
#pragma unroll
  for (int nt = 0; nt < 8; ++nt) {
#pragma unroll
    for (int kk = 0; kk < 4; ++kk) {
      bf8_t bw = *(const bf8_t*)(w2bf + (size_t)(nt * 16 + lr) * CC + kk * 32 + lh * 8);
#pragma unroll
      for (int mt = 0; mt < 2; ++mt) acc[mt][nt] = MFMA16(af2[mt][kk], bw, acc[mt][nt]);
    }
  }
#pragma unroll
  for (int mt = 0; mt < 2; ++mt)
#pragma unroll
    for (int nt = 0; nt < 8; ++nt)
#pragma unroll
      for (int r = 0; r < 4; ++r) {
        int posl = wave * 32 + mt * 16 + lh * 4 + r;
        int c = nt * 16 + lr;
        size_t p = (size_t)ii * NN + j0 + posl;
        float g = bf2f(g3t[posl * 128 + (((c >> 3) ^ (posl & 15)) * 8) + (c & 7)]);
        out[p * CC + c] = acc[mt][nt][r] * g;
      }
}

extern "C" void kernel_launch(void* const* d_in, const int* in_sizes, int n_in,
                              void* d_out, int out_size, void* d_ws, size_t ws_size,
                              hipStream_t stream) {
  (void)in_sizes; (void)n_in; (void)out_size; (void)ws_size;
  const float* x2d  = (const float*)d_in[0];
  const float* n1g  = (const float*)d_in[1];
  const float* n1b  = (const float*)d_in[2];
  const float* n2g  = (const float*)d_in[3];
  const float* n2b  = (const float*)d_in[4];
  const float* w1i  = (const float*)d_in[5];
  const float* b1i  = (const float*)d_in[6];
  const float* w1j  = (const float*)d_in[7];
  const float* b1j  = (const float*)d_in[8];
  const float* w1is = (const float*)d_in[9];
  const float* b1is = (const float*)d_in[10];
  const float* w1js = (const float*)d_in[11];
  const float* b1js = (const float*)d_in[12];
  const float* w2   = (const float*)d_in[13];
  const float* b2   = (const float*)d_in[14];
  const float* w3   = (const float*)d_in[15];
  const float* b3   = (const float*)d_in[16];

  char* ws = (char*)d_ws;
  unsigned short* wcat = (unsigned short*)ws;            // 192 KiB (padded to 256 KiB)
  size_t TELEMS = (size_t)CC * NN * NN;                  // 18,874,368
  unsigned short* i_s  = (unsigned short*)(ws + 262144); // 36 MiB [c][p]
  unsigned short* j_s  = i_s + TELEMS;                   // 36 MiB [c][p]
  unsigned short* g3   = j_s + TELEMS;                   // 36 MiB [p][c]
  unsigned short* x_ln = g3 + TELEMS;                    // 36 MiB [p][c]
  // out_pre (36 MiB bf16) aliases x_ln: x_ln dead after kP, kB runs after kP.
  unsigned short* out_pre = x_ln;
  float* outp = (float*)d_out;

  kInit<<<1248, 256, 0, stream>>>(w1i, w1is, w1j, w1js, w3, w2, wcat, x2d, n1g, n1b, x_ln);
  kP<<<1728, 256, 0, stream>>>(x_ln, wcat, b1i, b1is, b1j, b1js, b3, i_s, j_s, g3);
  kB<<<1152, 256, 0, stream>>>(i_s, j_s, out_pre);
  kC<<<1152, 256, 0, stream>>>(out_pre, n2g, n2b, wcat + 5 * CC * CC, b2, g3, outp);
}